// Round 9
// baseline (265.292 us; speedup 1.0000x reference)
//
#include <hip/hip_runtime.h>
#include <math.h>

// Problem constants (B=2, S=2048 -> N=4096 tokens)
#define NTOK 4096
#define DDIM 512
#define HDIM 2048
#define NEXP 16

// Fragment-tiled layouts: elem(e_or_t, row, k) =
//   ((tile16 * CK + (k>>3)) * 128) + (row&15)*8 + (k&7)
// so a 64-lane b128 load (lane*16B) fetches one MFMA fragment set, coalesced.
// GEMMs stage into LDS via global_load_lds and read frags with ds_read_b128.
// K-loops: 3-buffer, counted s_waitcnt vmcnt(4) + raw s_barrier (never drains
// to 0 mid-loop) so one stage stays in flight across every barrier [R3->R4].
// [R8 post-mortem: scan removal = 0 (launch gaps tiny); remaining time is in
// kernels. R9: (a) gather_xa deleted — gemm1 stages A DIRECTLY from a bf16
// copy of x (written by gating blocks) using per-lane token-gathered gld16;
// the 1 KB gld16 lane->LDS map (8*l ushorts) is exactly the fragment layout,
// so LDS contents are byte-identical to the old xa path. (b) s_setprio around
// fusedC's MFMA — fusedC has role-diverse waves (GEMM || wtrans), the regime
// where T5 pays.]

// Workspace layout (bytes). counts padded: one counter per 64 B line.
#define WS_COUNTS    0u            // 16 lines x 64 B = 1 KB
#define WS_EPOS      4096u         // NTOK*2 ints (32 KB)
#define WS_TOK       36864u        // NEXP*NTOK ints (256 KB)
#define WS_WL        299008u       // NEXP*NTOK floats (256 KB)
#define WS_XBF       1048576u      // bf16 copy of x: 4096*512*2 = 4 MB
#define WS_W1T       11534336u     // tiled [e][nt128][c64][16][8] bf16 = 33.5 MB
#define WS_W2T       45088768u     // tiled [e][nt32][c256][16][8] bf16 = 33.5 MB
#define WS_HB        78643200u     // tiled [t80][sub8][c256][16][8] bf16 = 41.9 MB
#define WS_YB        WS_W1T        // ybuf [4][8192][512] bf16 = 33.55 MB, aliases
                                   // W1T exactly (dead after gemm1)

typedef __attribute__((ext_vector_type(8))) short short8;
typedef __attribute__((ext_vector_type(4))) float floatx4;
typedef unsigned short ushort_t;

__device__ __forceinline__ ushort_t f2bf(float f) {
    unsigned u = __float_as_uint(f);
    u += 0x7fffu + ((u >> 16) & 1u);   // round-to-nearest-even
    return (ushort_t)(u >> 16);
}
__device__ __forceinline__ float bf2f(ushort_t u) {
    return __uint_as_float((unsigned)u << 16);
}
__device__ __forceinline__ unsigned pk2(float a, float b) {
    return (unsigned)f2bf(a) | ((unsigned)f2bf(b) << 16);
}

// async global->LDS, 16 B per lane: dst is wave-uniform base (+lane*16 in HW),
// src is per-lane.
__device__ __forceinline__ void gld16(const void* g, void* l) {
    __builtin_amdgcn_global_load_lds(
        (const __attribute__((address_space(1))) unsigned*)g,
        (__attribute__((address_space(3))) unsigned*)l, 16, 0, 0);
}

#define WAIT4_BAR() asm volatile("s_waitcnt vmcnt(4)\n\ts_barrier" ::: "memory")
#define WAIT0_BAR() asm volatile("s_waitcnt vmcnt(0)\n\ts_barrier" ::: "memory")

// Local replacement for the scan kernel: walk the 16 padded counters, find
// which expert owns 128-row tile t. Uniform scalar loads; ~50 cycles.
struct TileInfo { int e, m0, Me, aoff, total; };
__device__ __forceinline__ TileInfo tile_lookup(const int* __restrict__ counts,
                                                int t)
{
    TileInfo ti; ti.e = 0; ti.m0 = 0; ti.Me = 0; ti.aoff = 0;
    int total = 0, aacc = 0;
    #pragma unroll
    for (int j = 0; j < NEXP; ++j) {
        const int c = counts[j * 16];
        const int tj = (c + 127) >> 7;
        if (t >= total && t < total + tj) {
            ti.e = j; ti.m0 = (t - total) << 7; ti.Me = c; ti.aoff = aacc;
        }
        total += tj;
        aacc += c;
    }
    ti.total = total;
    return ti;
}

// ---- weight transpose tile: 32k x 256n, sequential 1 KB-per-row reads -----
// [R2: 256 B col-window reads @8 KB stride -> 2.3 TB/s row-activation bound;
// sequential rows + sibling n-window blocks adjacent in dispatch order.]
// LDS: packed bf16 k-pairs at [n][kpair], stride 17 u32. Output layout is the
// fragment-tiled Wt.
__device__ __forceinline__ void wtrans_tile(
    const float* __restrict__ src, ushort_t* __restrict__ dst,
    int C, int NT, int CK, int e, int ks, int nw, unsigned* lb, int tid)
{
    const int q = tid >> 4;            // local k-pair 0..15 (k rows 2q, 2q+1)
    const int c0 = (tid & 15) << 2;    // col offset within 64-col pass
    const float* sp = src + (size_t)e * (DDIM * HDIM)
                    + (size_t)(ks * 32 + 2 * q) * C + nw * 256;
    float4 va[4], vb[4];
    #pragma unroll
    for (int p = 0; p < 4; ++p) {
        va[p] = *(const float4*)(sp + c0 + p * 64);
        vb[p] = *(const float4*)(sp + C + c0 + p * 64);
    }
    #pragma unroll
    for (int p = 0; p < 4; ++p) {
        const int n = c0 + p * 64;
        lb[(n + 0) * 17 + q] = pk2(va[p].x, vb[p].x);
        lb[(n + 1) * 17 + q] = pk2(va[p].y, vb[p].y);
        lb[(n + 2) * 17 + q] = pk2(va[p].z, vb[p].z);
        lb[(n + 3) * 17 + q] = pk2(va[p].w, vb[p].w);
    }
    __syncthreads();
    const int nt = tid >> 4, nl = tid & 15;
    const int ntg = nw * 16 + nt;
    ushort_t* rbase = dst + ((size_t)e * NT + ntg) * ((size_t)CK * 128) + nl * 8;
    const unsigned* rp = lb + (nt * 16 + nl) * 17;
    #pragma unroll
    for (int kc = 0; kc < 4; ++kc) {
        const unsigned o0 = rp[kc * 4 + 0], o1 = rp[kc * 4 + 1];
        const unsigned o2 = rp[kc * 4 + 2], o3 = rp[kc * 4 + 3];
        *(uint4*)(rbase + (size_t)(ks * 4 + kc) * 128) = make_uint4(o0, o1, o2, o3);
    }
}

// ---- fusedA: blocks 0..511 gating (8 tok) + bf16 x copy, 512..2559 W1trans -
// Gating: LDS histogram -> <=16 global atomicAdds per block, own 64 B lines.
__global__ __launch_bounds__(256) void fusedA_kernel(
    const float* __restrict__ x, const float* __restrict__ Wg,
    const float* __restrict__ bg, int* __restrict__ counts,
    int* __restrict__ tok_list, float* __restrict__ w_list,
    int* __restrict__ epos, const float* __restrict__ W1,
    ushort_t* __restrict__ W1t, ushort_t* __restrict__ xbf)
{
    __shared__ __align__(16) float smem[4416];   // 17.7 KB, both paths
    __shared__ int lcnt[16], lbase[16];
    const int tid = threadIdx.x;
    int bid = blockIdx.x;

    if (bid >= 512) {
        // wtrans-W1: [512 k][2048 n]; NT=128, CK=64; 128 blocks/expert
        bid -= 512;
        const int e = bid >> 7, r = bid & 127;
        const int nw = r & 7, ks = r >> 3;       // nw fastest: rows covered
        wtrans_tile(W1, W1t, HDIM, 128, 64, e, ks, nw, (unsigned*)smem, tid);
        return;
    }

    // ---------------- gating ----------------
    float (*xs)[520] = (float(*)[520])smem;
    float (*lsm)[16][2] = (float(*)[16][2])(smem + 4160);
    const int t0 = bid * 8;
    const float* xg = x + (size_t)t0 * DDIM;
    #pragma unroll
    for (int p = 0; p < 4; ++p) {
        const int idx = p * 1024 + tid * 4;
        *(float4*)&xs[idx >> 9][idx & 511] = *(const float4*)(xg + idx);
    }
    if (tid < 16) lcnt[tid] = 0;
    __syncthreads();

    // bf16 copy of these 8 x rows (gemm1 A-source; coalesced 32 B/lane)
    {
        const int row = tid >> 5, col = (tid & 31) * 16;
        const float* sr = &xs[row][col];
        unsigned o[8];
        #pragma unroll
        for (int j = 0; j < 8; ++j) o[j] = pk2(sr[2 * j], sr[2 * j + 1]);
        ushort_t* xd = xbf + (size_t)(t0 + row) * DDIM + col;
        *(uint4*)(xd) = make_uint4(o[0], o[1], o[2], o[3]);
        *(uint4*)(xd + 8) = make_uint4(o[4], o[5], o[6], o[7]);
    }

    const int tl = tid >> 5, e = (tid >> 1) & 15, h = tid & 1;
    float a0 = 0.f, a1 = 0.f, a2 = 0.f, a3 = 0.f;
    #pragma unroll 8
    for (int it = 0; it < 64; ++it) {
        const int d = h * 256 + it * 4;
        const float4 xv = *(const float4*)&xs[tl][d];
        a0 = fmaf(xv.x, Wg[(d + 0) * 16 + e], a0);
        a1 = fmaf(xv.y, Wg[(d + 1) * 16 + e], a1);
        a2 = fmaf(xv.z, Wg[(d + 2) * 16 + e], a2);
        a3 = fmaf(xv.w, Wg[(d + 3) * 16 + e], a3);
    }
    lsm[tl][e][h] = (a0 + a1) + (a2 + a3);
    __syncthreads();

    int i0 = 0, i1 = -1, r0 = 0, r1 = 0;
    float w0 = 0.f, w1 = 0.f;
    const bool tokth = ((tid & 31) == 0);
    if (tokth) {
        float l[16];
        #pragma unroll
        for (int j = 0; j < NEXP; ++j) l[j] = lsm[tl][j][0] + lsm[tl][j][1] + bg[j];
        float m = -1e30f;
        #pragma unroll
        for (int j = 0; j < NEXP; ++j) m = fmaxf(m, l[j]);
        float s = 0.f;
        #pragma unroll
        for (int j = 0; j < NEXP; ++j) s += __expf(l[j] - m);
        float v0 = -1e30f;
        #pragma unroll
        for (int j = 0; j < NEXP; ++j)
            if (l[j] > v0) { v0 = l[j]; i0 = j; }
        float v1 = -1e30f;
        #pragma unroll
        for (int j = 0; j < NEXP; ++j)
            if (j != i0 && l[j] > v1) { v1 = l[j]; i1 = j; }
        w0 = __expf(v0 - m) / s;
        w1 = __expf(v1 - m) / s;
        r0 = atomicAdd(&lcnt[i0], 1);      // LDS atomics: local rank
        r1 = atomicAdd(&lcnt[i1], 1);
    }
    __syncthreads();
    if (tid < 16 && lcnt[tid] > 0)
        lbase[tid] = atomicAdd(&counts[tid * 16], lcnt[tid]);
    __syncthreads();
    if (tokth) {
        const int t = t0 + tl;
        const int p0 = lbase[i0] + r0;
        tok_list[i0 * NTOK + p0] = t;
        w_list[i0 * NTOK + p0] = w0;
        epos[t * 2 + 0] = (i0 << 16) | p0;
        const int p1 = lbase[i1] + r1;
        tok_list[i1 * NTOK + p1] = t;
        w_list[i1 * NTOK + p1] = w1;
        epos[t * 2 + 1] = (i1 << 16) | p1;
    }
}

// ---- fusedC: blocks 0..1279 GEMM1 (3-buf counted pipeline), rest wtrans-W2 -
// A staged from xbf via per-lane token-gathered gld16 (no xa/gather pass).
__global__ __launch_bounds__(256) void fusedC_kernel(
    const ushort_t* __restrict__ xbf, const int* __restrict__ tok_list,
    const ushort_t* __restrict__ W1t, const float* __restrict__ b1,
    const int* __restrict__ counts, ushort_t* __restrict__ hb,
    const float* __restrict__ W2, ushort_t* __restrict__ W2t)
{
    __shared__ __align__(16) ushort_t lds[24576];   // 48 KB: 3 x (A 8KB|B 8KB)
    const int tid = threadIdx.x;
    const int bid = blockIdx.x;

    if (bid >= 1280) {
        // wtrans-W2: [2048 k][512 n]; NT=32, CK=256; 128 blocks/expert
        const int wb = bid - 1280;
        const int e = wb >> 7, r = wb & 127;
        const int nw = r & 1, ks = r >> 1;
        wtrans_tile(W2, W2t, DDIM, 32, 256, e, ks, nw, (unsigned*)lds, tid);
        return;
    }

    // XCD-bijective swizzle (1280 = 8*160): n0-siblings + neighbor tiles
    // land on the same XCD's L2 -> A panel fetched once from HBM.
    const int swz = (bid & 7) * 160 + (bid >> 3);
    const int t = swz >> 4;
    const TileInfo ti = tile_lookup(counts, t);
    if (t >= ti.total) return;
    const int e = ti.e, m0 = ti.m0, Me = ti.Me;
    const int n0 = (swz & 15) << 7;
    const int lane = tid & 63, w = tid >> 6;
    const int fm = lane & 15, fq = lane >> 4;
    const int wr = (w >> 1) << 6, wc = (w & 1) << 6;

    // A-source: wave w stages row-tiles rt=2w, 2w+1. Lane l covers
    // (kchunk=l>>4, row=l&15): LDS dest 8*l ushorts == fragment layout.
    const int rtA = 2 * w, rtB = 2 * w + 1;
    const int arow = lane & 15, akq = lane >> 4;
    const int tokA = tok_list[e * NTOK + min(m0 + rtA * 16 + arow, Me - 1)];
    const int tokB = tok_list[e * NTOK + min(m0 + rtB * 16 + arow, Me - 1)];
    const ushort_t* gA0 = xbf + (size_t)tokA * DDIM + akq * 8;
    const ushort_t* gA1 = xbf + (size_t)tokB * DDIM + akq * 8;

    const ushort_t* gB = W1t + ((size_t)e * 128 + (n0 >> 4)) * 8192 + lane * 8;
    const int s0 = w, s1 = w + 4;   // this wave stages B chunks s0,s1

    #define G1_STAGE(d, kc) do {                                            \
        ushort_t* lb_ = &lds[(d) * 8192];                                   \
        gld16(gA0 + (kc) * 32, lb_ + rtA * 512);                            \
        gld16(gA1 + (kc) * 32, lb_ + rtB * 512);                            \
        gld16(gB + (size_t)s0 * 8192 + (kc) * 512, lb_ + 4096 + s0 * 512);  \
        gld16(gB + (size_t)s1 * 8192 + (kc) * 512, lb_ + 4096 + s1 * 512);  \
    } while (0)

    #define G1_COMPUTE(cur) do {                                            \
        const ushort_t* la = &lds[(cur) * 8192 + ((w >> 1) * 4) * 512 + lane * 8]; \
        const ushort_t* lbB = &lds[(cur) * 8192 + 4096 + ((w & 1) * 4) * 512 + lane * 8]; \
        short8 af[4], bf[4];                                                \
        _Pragma("unroll")                                                   \
        for (int i = 0; i < 4; ++i) af[i] = *(const short8*)(la + i * 512); \
        _Pragma("unroll")                                                   \
        for (int j = 0; j < 4; ++j) bf[j] = *(const short8*)(lbB + j * 512);\
        __builtin_amdgcn_s_setprio(1);                                      \
        _Pragma("unroll")                                                   \
        for (int i = 0; i < 4; ++i)                                         \
            _Pragma("unroll")                                               \
            for (int j = 0; j < 4; ++j)                                     \
                acc[i][j] = __builtin_amdgcn_mfma_f32_16x16x32_bf16(        \
                    af[i], bf[j], acc[i][j], 0, 0, 0);                      \
        __builtin_amdgcn_s_setprio(0);                                      \
    } while (0)

    G1_STAGE(0, 0);
    G1_STAGE(1, 1);
    floatx4 acc[4][4] = {};
    int cur = 0;
    #pragma unroll 1
    for (int kc = 0; kc < 14; ++kc) {
        WAIT4_BAR();               // stage kc landed (kc+1 stays in flight)
        const int nb = (kc + 2) % 3;
        G1_STAGE(nb, kc + 2);      // overwrites buf computed at kc-1 (safe: bar)
        G1_COMPUTE(cur);
        cur = (cur == 2) ? 0 : cur + 1;
    }
    WAIT4_BAR();
    G1_COMPUTE(cur);               // kc=14, cur=2
    cur = (cur == 2) ? 0 : cur + 1;
    WAIT0_BAR();
    G1_COMPUTE(cur);               // kc=15, cur=0
    __syncthreads();               // all LDS reads done before epilogue reuse
    #undef G1_STAGE
    #undef G1_COMPUTE

    ushort_t* ls = lds;            // epilogue scratch, 32 KB of the 48
    #pragma unroll
    for (int j = 0; j < 4; ++j) {
        const float bias = b1[(size_t)e * HDIM + n0 + wc + j * 16 + fm];
        #pragma unroll
        for (int i = 0; i < 4; ++i)
            #pragma unroll
            for (int r = 0; r < 4; ++r) {
                const int row = wr + i * 16 + fq * 4 + r;
                ls[row * 128 + wc + j * 16 + fm] =
                    f2bf(fmaxf(acc[i][j][r] + bias, 0.f));
            }
    }
    __syncthreads();
    ushort_t* hbase = hb + (size_t)t * 262144 + (size_t)(n0 >> 3) * 128;
    #pragma unroll
    for (int p = 0; p < 8; ++p) {
        const int unit = tid + p * 256;
        const int row = unit >> 4, c16 = unit & 15;
        *(short8*)(hbase + (size_t)(row >> 4) * 32768 + (size_t)c16 * 128
                   + (row & 15) * 8) = *(const short8*)&ls[row * 128 + c16 * 8];
    }
}

// ---- GEMM2: same pipeline, K=2048 split-K=4, bf16 partials to ybuf --------
__global__ __launch_bounds__(256) void gemm2_mfma(
    const ushort_t* __restrict__ hb, const ushort_t* __restrict__ W2t,
    const float* __restrict__ b2, const float* __restrict__ w_list,
    const int* __restrict__ counts, ushort_t* __restrict__ yb)
{
    const int bid = blockIdx.x;
    // XCD-bijective swizzle over 1280 = (kz*80 + t)*4 + n0i
    const int swz = (bid & 7) * 160 + (bid >> 3);
    const int n0i = swz & 3;
    const int q_ = swz >> 2;           // 0..319
    const int kz = q_ / 80;
    const int t = q_ - kz * 80;
    const TileInfo ti = tile_lookup(counts, t);
    if (t >= ti.total) return;
    const int e = ti.e, m0 = ti.m0, Me = ti.Me, aoff = ti.aoff;
    const int n0 = n0i << 7;
    const int tid = threadIdx.x, lane = tid & 63, w = tid >> 6;
    const int fm = lane & 15, fq = lane >> 4;
    const int wr = (w >> 1) << 6, wc = (w & 1) << 6;

    __shared__ __align__(16) ushort_t lds[24576];   // 48 KB

    const ushort_t* gA = hb + (size_t)t * 262144 + (size_t)kz * 8192 + lane * 8;
    const ushort_t* gB = W2t + ((size_t)e * 32 + (n0 >> 4)) * 32768
                       + (size_t)kz * 8192 + lane * 8;
    const int s0 = w, s1 = w + 4;

    #define G2_STAGE(d, kc) do {                                            \
        ushort_t* lb_ = &lds[(d) * 8192];                                   \
        gld16(gA + (size_t)s0 * 32768 + (kc) * 512, lb_ + s0 * 512);        \
        gld16(gA + (size_t)s1 * 32768 + (kc) * 512, lb_ + s1 * 512);        \
        gld16(gB + (size_t)s0 * 32768 + (kc) * 512, lb_ + 4096 + s0 * 512); \
        gld16(gB + (size_t)s1 * 32768 + (kc) * 512, lb_ + 4096 + s1 * 512); \
    } while (0)

    #define G2_COMPUTE(cur) do {                                            \
        const ushort_t* la = &lds[(cur) * 8192 + ((w >> 1) * 4) * 512 + lane * 8]; \
        const ushort_t* lbB = &lds[(cur) * 8192 + 4096 + ((w & 1) * 4) * 512 + lane * 8]; \
        short8 af[4], bf[4];                                                \
        _Pragma("unroll")                                                   \
        for (int i = 0; i < 4; ++i) af[i] = *(const short8*)(la + i * 512); \
        _Pragma("unroll")                                                   \
        for (int j = 0; j < 4; ++j) bf[j] = *(const short8*)(lbB + j * 512);\
        _Pragma("unroll")                                                   \
        for (int i = 0; i < 4; ++i)                                         \
            _Pragma("unroll")                                               \
            for (int j = 0; j < 4; ++j)                                     \
                acc[i][j] = __builtin_amdgcn_mfma_f32_16x16x32_bf16(        \
                    af[i], bf[j], acc[i][j], 0, 0, 0);                      \
    } while (0)

    G2_STAGE(0, 0);
    G2_STAGE(1, 1);
    floatx4 acc[4][4] = {};
    int cur = 0;
    #pragma unroll 1
    for (int kc = 0; kc < 14; ++kc) {
        WAIT4_BAR();
        const int nb = (kc + 2) % 3;
        G2_STAGE(nb, kc + 2);
        G2_COMPUTE(cur);
        cur = (cur == 2) ? 0 : cur + 1;
    }
    WAIT4_BAR();
    G2_COMPUTE(cur);               // kc=14
    cur = (cur == 2) ? 0 : cur + 1;
    WAIT0_BAR();
    G2_COMPUTE(cur);               // kc=15
    __syncthreads();
    #undef G2_STAGE
    #undef G2_COMPUTE

    ushort_t* ls = lds;
    #pragma unroll
    for (int j = 0; j < 4; ++j) {
        const float bias = (kz == 0) ? b2[(size_t)e * DDIM + n0 + wc + j * 16 + fm] : 0.f;
        #pragma unroll
        for (int i = 0; i < 4; ++i)
            #pragma unroll
            for (int r = 0; r < 4; ++r) {
                const int row = wr + i * 16 + fq * 4 + r;
                const float gw = w_list[e * NTOK + min(m0 + row, Me - 1)];
                ls[row * 128 + wc + j * 16 + fm] = f2bf(gw * (acc[i][j][r] + bias));
            }
    }
    __syncthreads();
    ushort_t* ybase = yb + (size_t)kz * (8192 * 512) + n0;
    #pragma unroll
    for (int p = 0; p < 8; ++p) {
        const int unit = tid + p * 256;
        const int row = unit >> 4, c16 = unit & 15;
        if (m0 + row < Me)
            *(short8*)(ybase + (size_t)(aoff + m0 + row) * 512 + c16 * 8)
                = *(const short8*)&ls[row * 128 + c16 * 8];
    }
}

// out = LayerNorm(x + sum_{kz=0..3} (y[kz][r0] + y[kz][r1])) * gamma + beta
__global__ __launch_bounds__(256) void ln_kernel(
    const float* __restrict__ x, const ushort_t* __restrict__ yb,
    const int* __restrict__ epos, const int* __restrict__ counts,
    const float* __restrict__ gamma, const float* __restrict__ beta,
    float* __restrict__ out)
{
    const int t = blockIdx.x * 4 + (threadIdx.x >> 6);
    const int lane = threadIdx.x & 63;
    const int d0 = lane * 8;

    const int p0 = epos[2 * t + 0];
    const int p1 = epos[2 * t + 1];
    const int e0 = p0 >> 16, e1 = p1 >> 16;
    int off0 = 0, off1 = 0;
    #pragma unroll
    for (int j = 0; j < NEXP; ++j) {
        const int c = counts[j * 16];
        off0 += (j < e0) ? c : 0;
        off1 += (j < e1) ? c : 0;
    }
    const size_t r0 = (size_t)(off0 + (p0 & 0xFFFF));
    const size_t r1 = (size_t)(off1 + (p1 & 0xFFFF));

    short8 ys[8];
    #pragma unroll
    for (int kz = 0; kz < 4; ++kz) {
        ys[kz * 2 + 0] = *(const short8*)(yb + (size_t)kz * (8192 * 512) + r0 * 512 + d0);
        ys[kz * 2 + 1] = *(const short8*)(yb + (size_t)kz * (8192 * 512) + r1 * 512 + d0);
    }
    float xv[8];
    *(float4*)&xv[0] = *(const float4*)(x + (size_t)t * DDIM + d0);
    *(float4*)&xv[4] = *(const float4*)(x + (size_t)t * DDIM + d0 + 4);

    float v[8];
    float s = 0.f;
    #pragma unroll
    for (int i = 0; i < 8; ++i) {
        float a = xv[i];
        #pragma unroll
        for (int q = 0; q < 8; ++q) a += bf2f((ushort_t)ys[q][i]);
        v[i] = a;
        s += a;
    }
    #pragma unroll
    for (int o = 32; o > 0; o >>= 1) s += __shfl_xor(s, o, 64);
    const float mu = s * (1.f / DDIM);
    float q = 0.f;
    #pragma unroll
    for (int i = 0; i < 8; ++i) { const float d_ = v[i] - mu; q = fmaf(d_, d_, q); }
    #pragma unroll
    for (int o = 32; o > 0; o >>= 1) q += __shfl_xor(q, o, 64);
    const float rstd = rsqrtf(q * (1.f / DDIM) + 1e-5f);

    float g[8], bt[8], o8[8];
    *(float4*)&g[0] = *(const float4*)(gamma + d0);
    *(float4*)&g[4] = *(const float4*)(gamma + d0 + 4);
    *(float4*)&bt[0] = *(const float4*)(beta + d0);
    *(float4*)&bt[4] = *(const float4*)(beta + d0 + 4);
    #pragma unroll
    for (int i = 0; i < 8; ++i) o8[i] = (v[i] - mu) * rstd * g[i] + bt[i];
    *(float4*)(out + (size_t)t * DDIM + d0) = *(float4*)&o8[0];
    *(float4*)(out + (size_t)t * DDIM + d0 + 4) = *(float4*)&o8[4];
}

extern "C" void kernel_launch(void* const* d_in, const int* in_sizes, int n_in,
                              void* d_out, int out_size, void* d_ws, size_t ws_size,
                              hipStream_t stream) {
    const float* x     = (const float*)d_in[0];
    const float* Wg    = (const float*)d_in[1];
    const float* bg    = (const float*)d_in[2];
    const float* W1    = (const float*)d_in[3];
    const float* b1    = (const float*)d_in[4];
    const float* W2    = (const float*)d_in[5];
    const float* b2    = (const float*)d_in[6];
    const float* gamma = (const float*)d_in[7];
    const float* beta  = (const float*)d_in[8];
    float* out = (float*)d_out;

    char* ws = (char*)d_ws;
    int*      counts   = (int*)(ws + WS_COUNTS);
    int*      epos     = (int*)(ws + WS_EPOS);
    int*      tok_list = (int*)(ws + WS_TOK);
    float*    w_list   = (float*)(ws + WS_WL);
    ushort_t* xbf      = (ushort_t*)(ws + WS_XBF);
    ushort_t* W1t      = (ushort_t*)(ws + WS_W1T);
    ushort_t* W2t      = (ushort_t*)(ws + WS_W2T);
    ushort_t* hb       = (ushort_t*)(ws + WS_HB);
    ushort_t* yb       = (ushort_t*)(ws + WS_YB);   // aliases W1t (dead by then)

    hipMemsetAsync(counts, 0, 1024, stream);
    fusedA_kernel<<<2560, 256, 0, stream>>>(x, Wg, bg, counts, tok_list, w_list,
                                            epos, W1, W1t, xbf);
    fusedC_kernel<<<3328, 256, 0, stream>>>(xbf, tok_list, W1t, b1, counts, hb,
                                            W2, W2t);
    gemm2_mfma<<<1280, 256, 0, stream>>>(hb, W2t, b2, w_list, counts, yb);
    ln_kernel<<<NTOK / 4, 256, 0, stream>>>(x, yb, epos, counts, gamma, beta, out);
}